// Round 5
// baseline (293.989 us; speedup 1.0000x reference)
//
#include <hip/hip_runtime.h>
#include <hip/hip_bf16.h>
#include <climits>

#define NATOMS 50000
#define NEDGES 100000
#define AD 64
#define BD 16
#define PITCH 1096           // LDS row pitch in bf16 elems (1088 + 8)
#define NR ((NEDGES + 31) / 32)   // 3125 wave-ranges of 32 edges
#define NBLK 256

typedef __bf16 bf16x8 __attribute__((ext_vector_type(8)));
typedef __bf16 bf16x4 __attribute__((ext_vector_type(4)));
typedef float  f32x16 __attribute__((ext_vector_type(16)));

// smallest "break" index >= p (break: q==0, q==NEDGES, or tgt[q]!=tgt[q-1]).
// All 64 lanes of the wave cooperate; common path = 1 ballot.
__device__ __forceinline__ int first_break(const int* __restrict__ pair, int p, const int lane) {
    while (true) {
        const int q = p + lane;
        bool brk;
        if (q == 0 || q >= NEDGES) brk = true;
        else brk = (pair[2 * q] != pair[2 * q - 2]);
        const unsigned long long m = __ballot(brk);
        if (m) {
            int r = p + (int)__builtin_ctzll(m);
            return r > NEDGES ? NEDGES : r;
        }
        p += 64;
    }
}

// MFMA + in-wave segmented inclusive scan over one chunk [g, g+32) ∩ [, e)
__device__ __forceinline__ void scan_slot(
    const int g, const int e,
    const float* __restrict__ atom, const float* __restrict__ bond,
    const int* __restrict__ pair,
    const __bf16* __restrict__ Brow0, const __bf16* __restrict__ Brow1,
    const int l31, const int half, const int h8,
    f32x16& acc0, f32x16& acc1, int& myTgt, bool& isLast)
{
    const int eA = g + l31;
    const bool validE = (eA < e);
    const int eAc = validE ? eA : 0;

    int ni = pair[2 * eAc + 1];
    if ((unsigned)ni >= NATOMS) ni = 0;
    const float* nbrRow  = atom + (long)ni * AD;
    const float* bondRow = bond + (long)eAc * BD;

    // half-row of nbr this lane needs: j = 16q + 8*half + r
    // (no zeroing of invalid lanes: their tgt=INT_MAX never matches a valid
    //  segment and they are never owners, so their garbage is never consumed)
    float nb[4][8];
    #pragma unroll
    for (int q = 0; q < 4; ++q) {
        const float4 lo = *reinterpret_cast<const float4*>(nbrRow + q * 16 + h8);
        const float4 hi = *reinterpret_cast<const float4*>(nbrRow + q * 16 + h8 + 4);
        nb[q][0] = lo.x; nb[q][1] = lo.y; nb[q][2] = lo.z; nb[q][3] = lo.w;
        nb[q][4] = hi.x; nb[q][5] = hi.y; nb[q][6] = hi.z; nb[q][7] = hi.w;
    }
    float bd[16];
    #pragma unroll
    for (int q = 0; q < 4; ++q) {
        const float4 v = *reinterpret_cast<const float4*>(bondRow + q * 4);
        bd[q * 4 + 0] = v.x; bd[q * 4 + 1] = v.y;
        bd[q * 4 + 2] = v.z; bd[q * 4 + 3] = v.w;
    }

    #pragma unroll
    for (int r = 0; r < 16; ++r) { acc0[r] = 0.f; acc1[r] = 0.f; }

    // main K: k = 16t + 8*half + r ;  b = t>>2 ; j = 16*(t&3) + 8*half + r
    #pragma unroll
    for (int t = 0; t < 64; ++t) {
        const float bv = bd[t >> 2];
        bf16x8 a;
        #pragma unroll
        for (int r = 0; r < 8; ++r) a[r] = (__bf16)(bv * nb[t & 3][r]);
        const int k0 = t * 16 + h8;
        const bf16x8 b0 = *reinterpret_cast<const bf16x8*>(Brow0 + k0);
        const bf16x8 b1 = *reinterpret_cast<const bf16x8*>(Brow1 + k0);
        // swapped operands: C[feature][edge], edge = l31
        acc0 = __builtin_amdgcn_mfma_f32_32x32x16_bf16(b0, a, acc0, 0, 0, 0);
        acc1 = __builtin_amdgcn_mfma_f32_32x32x16_bf16(b1, a, acc1, 0, 0, 0);
    }
    #pragma unroll
    for (int t = 64; t < 68; ++t) {   // bias rows, A-side vector = nbr
        bf16x8 a;
        #pragma unroll
        for (int r = 0; r < 8; ++r) a[r] = (__bf16)(nb[t - 64][r]);
        const int k0 = t * 16 + h8;
        const bf16x8 b0 = *reinterpret_cast<const bf16x8*>(Brow0 + k0);
        const bf16x8 b1 = *reinterpret_cast<const bf16x8*>(Brow1 + k0);
        acc0 = __builtin_amdgcn_mfma_f32_32x32x16_bf16(b0, a, acc0, 0, 0, 0);
        acc1 = __builtin_amdgcn_mfma_f32_32x32x16_bf16(b1, a, acc1, 0, 0, 0);
    }

    // segmented inclusive scan over sorted tgt within the 32-lane group
    myTgt = validE ? pair[2 * eA] : INT_MAX;
    #pragma unroll
    for (int d = 1; d < 32; d <<= 1) {
        const int srcTgt = __shfl_up(myTgt, (unsigned)d, 32);
        const bool same = (l31 >= d) && (srcTgt == myTgt);
        #pragma unroll
        for (int r = 0; r < 16; ++r) {
            const float v0 = __shfl_up(acc0[r], (unsigned)d, 32);
            const float v1 = __shfl_up(acc1[r], (unsigned)d, 32);
            if (same) { acc0[r] += v0; acc1[r] += v1; }
        }
    }

    const int nTgt = __shfl_down(myTgt, 1u, 32);
    isLast = validE && ((l31 == 31) || (nTgt != myTgt));
}

__global__ __launch_bounds__(512, 2)
void edgenet_kernel(const float* __restrict__ atom,
                    const float* __restrict__ bond,
                    const int*   __restrict__ pair,
                    const float* __restrict__ kern,
                    const float* __restrict__ bias,
                    float* __restrict__ out)
{
    __shared__ __bf16 Blds[64 * PITCH];   // B[i][k], k in [0,1088)

    const int tid = threadIdx.x;

    // ---- stage B = [kernel | bias] into LDS as bf16 (once per block) ----
    for (int q = tid; q < (16 * 4096) / 4; q += 512) {
        const int idx = q * 4;                  // flat: b*4096 + i*64 + j
        const int b = idx >> 12;
        const int i = (idx >> 6) & 63;
        const int j = idx & 63;
        const float4 v = *reinterpret_cast<const float4*>(kern + idx);
        bf16x4 w;
        w[0] = (__bf16)v.x; w[1] = (__bf16)v.y; w[2] = (__bf16)v.z; w[3] = (__bf16)v.w;
        *reinterpret_cast<bf16x4*>(Blds + i * PITCH + (b << 6) + j) = w;
    }
    for (int q = tid; q < 4096 / 4; q += 512) {
        const int idx = q * 4;
        const int i = idx >> 6;
        const int j = idx & 63;
        const float4 v = *reinterpret_cast<const float4*>(bias + idx);
        bf16x4 w;
        w[0] = (__bf16)v.x; w[1] = (__bf16)v.y; w[2] = (__bf16)v.z; w[3] = (__bf16)v.w;
        *reinterpret_cast<bf16x4*>(Blds + i * PITCH + 1024 + j) = w;
    }
    __syncthreads();   // the ONLY barrier in the kernel

    const int wave = tid >> 6;
    const int lane = tid & 63;
    const int l31  = lane & 31;
    const int half = lane >> 5;
    const int h8   = half * 8;

    const __bf16* __restrict__ Brow0 = Blds + l31 * PITCH;         // features 0..31
    const __bf16* __restrict__ Brow1 = Blds + (32 + l31) * PITCH;  // features 32..63

    // contiguous range band per block: every CU gets 12-13 range-units
    const int r0 = (NR * blockIdx.x) / NBLK;
    const int r1 = (NR * (blockIdx.x + 1)) / NBLK;

    for (int u = r0 + wave; u < r1; u += 8) {
        const int p0 = u * 32;
        int p1 = p0 + 32; if (p1 > NEDGES) p1 = NEDGES;
        const int s = first_break(pair, p0, lane);
        const int e = first_break(pair, p1, lane);
        if (s >= e) continue;   // a single long segment swallowed this window

        int carryTgt = INT_MIN;
        f32x16 c0, c1;
        #pragma unroll
        for (int r = 0; r < 16; ++r) { c0[r] = 0.f; c1[r] = 0.f; }

        for (int g = s; g < e; g += 32) {
            const int w = (e - g < 32) ? (e - g) : 32;

            f32x16 acc0, acc1; int myTgt; bool isLast;
            scan_slot(g, e, atom, bond, pair, Brow0, Brow1,
                      l31, half, h8, acc0, acc1, myTgt, isLast);

            // fold in carry from previous chunk of this range (same segment)
            if (myTgt == carryTgt) {
                #pragma unroll
                for (int r = 0; r < 16; ++r) { acc0[r] += c0[r]; acc1[r] += c1[r]; }
            }

            const int lastTgt = __shfl(myTgt, w - 1, 32);
            const bool cont = (g + 32 < e) && (lastTgt == pair[2 * (g + 32)]);

            const bool owner = isLast && !(cont && (l31 == w - 1));
            if (owner) {
                float* o = out + (long)myTgt * AD;
                #pragma unroll
                for (int rq = 0; rq < 4; ++rq) {
                    float4 v0, v1;
                    v0.x = acc0[rq*4+0]; v0.y = acc0[rq*4+1]; v0.z = acc0[rq*4+2]; v0.w = acc0[rq*4+3];
                    v1.x = acc1[rq*4+0]; v1.y = acc1[rq*4+1]; v1.z = acc1[rq*4+2]; v1.w = acc1[rq*4+3];
                    *reinterpret_cast<float4*>(o + 8 * rq + 4 * half)      = v0;
                    *reinterpret_cast<float4*>(o + 32 + 8 * rq + 4 * half) = v1;
                }
            }

            if (cont) {   // wave-uniform branch
                #pragma unroll
                for (int r = 0; r < 16; ++r) {
                    c0[r] = __shfl(acc0[r], w - 1, 32);
                    c1[r] = __shfl(acc1[r], w - 1, 32);
                }
                carryTgt = lastTgt;
            } else {
                carryTgt = INT_MIN;
            }
        }
    }
}

extern "C" void kernel_launch(void* const* d_in, const int* in_sizes, int n_in,
                              void* d_out, int out_size, void* d_ws, size_t ws_size,
                              hipStream_t stream) {
    const float* atom = (const float*)d_in[0];
    const float* bond = (const float*)d_in[1];
    const int*   pair = (const int*)d_in[2];
    const float* kern = (const float*)d_in[3];
    const float* bias = (const float*)d_in[4];
    float* out = (float*)d_out;

    hipMemsetAsync(d_out, 0, (size_t)out_size * sizeof(float), stream);

    edgenet_kernel<<<NBLK, 512, 0, stream>>>(atom, bond, pair, kern, bias, out);
}

// Round 6
// 174.019 us; speedup vs baseline: 1.6894x; 1.6894x over previous
//
#include <hip/hip_runtime.h>
#include <hip/hip_bf16.h>
#include <climits>

#define NATOMS 50000
#define NEDGES 100000
#define AD 64
#define BD 16
#define PITCH 1096            // LDS row pitch in bf16 elems (1088 + 8)
#define NR ((NEDGES + 31) / 32)   // 3125 wave-ranges of 32 edges
#define NBANDS 256
#define NBLK (NBANDS * 2)     // x2 feature-halves; 2 blocks/CU co-resident

typedef __bf16 bf16x8 __attribute__((ext_vector_type(8)));
typedef __bf16 bf16x4 __attribute__((ext_vector_type(4)));
typedef float  f32x16 __attribute__((ext_vector_type(16)));

// smallest "break" index >= p (break: q==0, q==NEDGES, or tgt[q]!=tgt[q-1]).
__device__ __forceinline__ int first_break(const int* __restrict__ pair, int p, const int lane) {
    while (true) {
        const int q = p + lane;
        bool brk;
        if (q == 0 || q >= NEDGES) brk = true;
        else brk = (pair[2 * q] != pair[2 * q - 2]);
        const unsigned long long m = __ballot(brk);
        if (m) {
            int r = p + (int)__builtin_ctzll(m);
            return r > NEDGES ? NEDGES : r;
        }
        p += 64;
    }
}

// MFMA + in-wave segmented inclusive scan over one chunk [g, g+32) ∩ [, e)
// for 32 features (this block's half). C[feature][edge], edge = l31.
__device__ __forceinline__ void scan_slot(
    const int g, const int e,
    const float* __restrict__ atom, const float* __restrict__ bond,
    const int* __restrict__ pair,
    const __bf16* __restrict__ Brow,
    const int l31, const int half, const int h8,
    f32x16& acc, int& myTgt, bool& isLast)
{
    const int eA = g + l31;
    const bool validE = (eA < e);
    const int eAc = validE ? eA : 0;

    int ni = pair[2 * eAc + 1];
    if ((unsigned)ni >= NATOMS) ni = 0;
    const float* nbrRow  = atom + (long)ni * AD;
    const float* bondRow = bond + (long)eAc * BD;

    // half-row of nbr this lane needs: j = 16q + 8*half + r
    // (invalid lanes' garbage is never consumed: tgt=INT_MAX never matches)
    float nb[4][8];
    #pragma unroll
    for (int q = 0; q < 4; ++q) {
        const float4 lo = *reinterpret_cast<const float4*>(nbrRow + q * 16 + h8);
        const float4 hi = *reinterpret_cast<const float4*>(nbrRow + q * 16 + h8 + 4);
        nb[q][0] = lo.x; nb[q][1] = lo.y; nb[q][2] = lo.z; nb[q][3] = lo.w;
        nb[q][4] = hi.x; nb[q][5] = hi.y; nb[q][6] = hi.z; nb[q][7] = hi.w;
    }
    float bd[16];
    #pragma unroll
    for (int q = 0; q < 4; ++q) {
        const float4 v = *reinterpret_cast<const float4*>(bondRow + q * 4);
        bd[q * 4 + 0] = v.x; bd[q * 4 + 1] = v.y;
        bd[q * 4 + 2] = v.z; bd[q * 4 + 3] = v.w;
    }

    #pragma unroll
    for (int r = 0; r < 16; ++r) acc[r] = 0.f;

    // main K: k = 16t + 8*half + r ;  b = t>>2 ; j = 16*(t&3) + 8*half + r
    #pragma unroll
    for (int t = 0; t < 64; ++t) {
        const float bv = bd[t >> 2];
        bf16x8 a;
        #pragma unroll
        for (int r = 0; r < 8; ++r) a[r] = (__bf16)(bv * nb[t & 3][r]);
        const bf16x8 b0 = *reinterpret_cast<const bf16x8*>(Brow + t * 16 + h8);
        acc = __builtin_amdgcn_mfma_f32_32x32x16_bf16(b0, a, acc, 0, 0, 0);
    }
    #pragma unroll
    for (int t = 64; t < 68; ++t) {   // bias rows, A-side vector = nbr
        bf16x8 a;
        #pragma unroll
        for (int r = 0; r < 8; ++r) a[r] = (__bf16)(nb[t - 64][r]);
        const bf16x8 b0 = *reinterpret_cast<const bf16x8*>(Brow + t * 16 + h8);
        acc = __builtin_amdgcn_mfma_f32_32x32x16_bf16(b0, a, acc, 0, 0, 0);
    }

    // segmented inclusive scan over sorted tgt within the 32-lane group
    myTgt = validE ? pair[2 * eA] : INT_MAX;
    #pragma unroll
    for (int d = 1; d < 32; d <<= 1) {
        const int srcTgt = __shfl_up(myTgt, (unsigned)d, 32);
        const bool same = (l31 >= d) && (srcTgt == myTgt);
        #pragma unroll
        for (int r = 0; r < 16; ++r) {
            const float v = __shfl_up(acc[r], (unsigned)d, 32);
            if (same) acc[r] += v;
        }
    }

    const int nTgt = __shfl_down(myTgt, 1u, 32);
    isLast = validE && ((l31 == 31) || (nTgt != myTgt));
}

__global__ __launch_bounds__(512, 2)
void edgenet_kernel(const float* __restrict__ atom,
                    const float* __restrict__ bond,
                    const int*   __restrict__ pair,
                    const float* __restrict__ kern,
                    const float* __restrict__ bias,
                    float* __restrict__ out)
{
    __shared__ __bf16 Blds[32 * PITCH];   // B-half [i_local][k], 70 KB

    const int tid  = threadIdx.x;
    const int fh   = blockIdx.x & 1;          // feature half: cols fh*32..fh*32+31
    const int band = blockIdx.x >> 1;         // edge band

    // ---- stage this half of B = [kernel | bias] into LDS as bf16 ----
    // kern half: 16(b) x 32(i_local) x 16(j-quad) = 8192 quads
    for (int q = tid; q < 8192; q += 512) {
        const int j  = (q & 15) * 4;
        const int il = (q >> 4) & 31;
        const int b  = q >> 9;
        const float4 v = *reinterpret_cast<const float4*>(
            kern + b * 4096 + (fh * 32 + il) * 64 + j);
        bf16x4 w;
        w[0] = (__bf16)v.x; w[1] = (__bf16)v.y; w[2] = (__bf16)v.z; w[3] = (__bf16)v.w;
        *reinterpret_cast<bf16x4*>(Blds + il * PITCH + (b << 6) + j) = w;
    }
    // bias half: 32(i_local) x 16(j-quad) = 512 quads
    {
        const int q  = tid;
        const int j  = (q & 15) * 4;
        const int il = q >> 4;
        const float4 v = *reinterpret_cast<const float4*>(
            bias + (fh * 32 + il) * 64 + j);
        bf16x4 w;
        w[0] = (__bf16)v.x; w[1] = (__bf16)v.y; w[2] = (__bf16)v.z; w[3] = (__bf16)v.w;
        *reinterpret_cast<bf16x4*>(Blds + il * PITCH + 1024 + j) = w;
    }
    __syncthreads();   // the ONLY barrier in the kernel

    const int wave = tid >> 6;
    const int lane = tid & 63;
    const int l31  = lane & 31;
    const int half = lane >> 5;
    const int h8   = half * 8;

    const __bf16* __restrict__ Brow = Blds + l31 * PITCH;   // feature fh*32 + l31

    const int r0 = (NR * band) / NBANDS;
    const int r1 = (NR * (band + 1)) / NBANDS;

    for (int u = r0 + wave; u < r1; u += 8) {
        const int p0 = u * 32;
        int p1 = p0 + 32; if (p1 > NEDGES) p1 = NEDGES;
        const int s = first_break(pair, p0, lane);
        const int e = first_break(pair, p1, lane);
        if (s >= e) continue;   // a long segment swallowed this window

        int carryTgt = INT_MIN;
        f32x16 c;
        #pragma unroll
        for (int r = 0; r < 16; ++r) c[r] = 0.f;

        for (int g = s; g < e; g += 32) {
            const int w = (e - g < 32) ? (e - g) : 32;

            f32x16 acc; int myTgt; bool isLast;
            scan_slot(g, e, atom, bond, pair, Brow, l31, half, h8, acc, myTgt, isLast);

            if (myTgt == carryTgt) {
                #pragma unroll
                for (int r = 0; r < 16; ++r) acc[r] += c[r];
            }

            const int lastTgt = __shfl(myTgt, w - 1, 32);
            const bool cont = (g + 32 < e) && (lastTgt == pair[2 * (g + 32)]);

            const bool owner = isLast && !(cont && (l31 == w - 1));
            if (owner) {
                float* o = out + (long)myTgt * AD + fh * 32;
                #pragma unroll
                for (int rq = 0; rq < 4; ++rq) {
                    float4 v;
                    v.x = acc[rq*4+0]; v.y = acc[rq*4+1]; v.z = acc[rq*4+2]; v.w = acc[rq*4+3];
                    *reinterpret_cast<float4*>(o + 8 * rq + 4 * half) = v;
                }
            }

            if (cont) {   // wave-uniform branch
                #pragma unroll
                for (int r = 0; r < 16; ++r) c[r] = __shfl(acc[r], w - 1, 32);
                carryTgt = lastTgt;
            } else {
                carryTgt = INT_MIN;
            }
        }
    }
}

extern "C" void kernel_launch(void* const* d_in, const int* in_sizes, int n_in,
                              void* d_out, int out_size, void* d_ws, size_t ws_size,
                              hipStream_t stream) {
    const float* atom = (const float*)d_in[0];
    const float* bond = (const float*)d_in[1];
    const int*   pair = (const int*)d_in[2];
    const float* kern = (const float*)d_in[3];
    const float* bias = (const float*)d_in[4];
    float* out = (float*)d_out;

    hipMemsetAsync(d_out, 0, (size_t)out_size * sizeof(float), stream);

    edgenet_kernel<<<NBLK, 512, 0, stream>>>(atom, bond, pair, kern, bias, out);
}

// Round 7
// 69.986 us; speedup vs baseline: 4.2007x; 2.4865x over previous
//
#include <hip/hip_runtime.h>
#include <hip/hip_bf16.h>
#include <climits>

#define NATOMS 50000
#define NEDGES 100000
#define AD 64
#define BD 16
#define PITCH 1096            // LDS row pitch in bf16 elems (1088 + 8)
#define NR ((NEDGES + 31) / 32)   // 3125 wave-ranges of 32 edges
#define NBANDS 256
#define NBLK (NBANDS * 2)     // x2 feature-halves; 2 blocks/CU co-resident

typedef __bf16 bf16x8 __attribute__((ext_vector_type(8)));
typedef __bf16 bf16x4 __attribute__((ext_vector_type(4)));
typedef float  f32x16 __attribute__((ext_vector_type(16)));

// smallest "break" index >= p (break: q==0, q==NEDGES, or tgt[q]!=tgt[q-1]).
__device__ __forceinline__ int first_break(const int* __restrict__ pair, int p, const int lane) {
    while (true) {
        const int q = p + lane;
        bool brk;
        if (q == 0 || q >= NEDGES) brk = true;
        else brk = (pair[2 * q] != pair[2 * q - 2]);
        const unsigned long long m = __ballot(brk);
        if (m) {
            int r = p + (int)__builtin_ctzll(m);
            return r > NEDGES ? NEDGES : r;
        }
        p += 64;
    }
}

// MFMA + in-wave segmented inclusive scan over one chunk [g, g+32) ∩ [, e)
// for 32 features (this block's half). C[feature][edge], edge = l31.
__device__ __forceinline__ void scan_slot(
    const int g, const int e,
    const float* __restrict__ atom, const float* __restrict__ bond,
    const int* __restrict__ pair,
    const __bf16* __restrict__ Brow,
    const int l31, const int half, const int h8,
    f32x16& acc, int& myTgt, bool& isLast)
{
    const int eA = g + l31;
    const bool validE = (eA < e);
    const int eAc = validE ? eA : 0;

    int ni = pair[2 * eAc + 1];
    if ((unsigned)ni >= NATOMS) ni = 0;
    const float* nbrRow  = atom + (long)ni * AD;
    const float* bondRow = bond + (long)eAc * BD;

    // half-row of nbr this lane needs: j = 16q + 8*half + r
    // (invalid lanes' garbage is never consumed: tgt=INT_MAX never matches)
    float nb[4][8];
    #pragma unroll
    for (int q = 0; q < 4; ++q) {
        const float4 lo = *reinterpret_cast<const float4*>(nbrRow + q * 16 + h8);
        const float4 hi = *reinterpret_cast<const float4*>(nbrRow + q * 16 + h8 + 4);
        nb[q][0] = lo.x; nb[q][1] = lo.y; nb[q][2] = lo.z; nb[q][3] = lo.w;
        nb[q][4] = hi.x; nb[q][5] = hi.y; nb[q][6] = hi.z; nb[q][7] = hi.w;
    }
    float bd[16];
    #pragma unroll
    for (int q = 0; q < 4; ++q) {
        const float4 v = *reinterpret_cast<const float4*>(bondRow + q * 4);
        bd[q * 4 + 0] = v.x; bd[q * 4 + 1] = v.y;
        bd[q * 4 + 2] = v.z; bd[q * 4 + 3] = v.w;
    }

    #pragma unroll
    for (int r = 0; r < 16; ++r) acc[r] = 0.f;

    // main K: k = 16t + 8*half + r ;  b = t>>2 ; j = 16*(t&3) + 8*half + r
    #pragma unroll
    for (int t = 0; t < 64; ++t) {
        const float bv = bd[t >> 2];
        bf16x8 a;
        #pragma unroll
        for (int r = 0; r < 8; ++r) a[r] = (__bf16)(bv * nb[t & 3][r]);
        const bf16x8 b0 = *reinterpret_cast<const bf16x8*>(Brow + t * 16 + h8);
        acc = __builtin_amdgcn_mfma_f32_32x32x16_bf16(b0, a, acc, 0, 0, 0);
    }
    #pragma unroll
    for (int t = 64; t < 68; ++t) {   // bias rows, A-side vector = nbr
        bf16x8 a;
        #pragma unroll
        for (int r = 0; r < 8; ++r) a[r] = (__bf16)(nb[t - 64][r]);
        const bf16x8 b0 = *reinterpret_cast<const bf16x8*>(Brow + t * 16 + h8);
        acc = __builtin_amdgcn_mfma_f32_32x32x16_bf16(b0, a, acc, 0, 0, 0);
    }

    // segmented inclusive scan over sorted tgt within the 32-lane group
    myTgt = validE ? pair[2 * eA] : INT_MAX;
    #pragma unroll
    for (int d = 1; d < 32; d <<= 1) {
        const int srcTgt = __shfl_up(myTgt, (unsigned)d, 32);
        const bool same = (l31 >= d) && (srcTgt == myTgt);
        #pragma unroll
        for (int r = 0; r < 16; ++r) {
            const float v = __shfl_up(acc[r], (unsigned)d, 32);
            if (same) acc[r] += v;
        }
    }

    const int nTgt = __shfl_down(myTgt, 1u, 32);
    isLast = validE && ((l31 == 31) || (nTgt != myTgt));
}

__global__ __launch_bounds__(512, 4)
void edgenet_kernel(const float* __restrict__ atom,
                    const float* __restrict__ bond,
                    const int*   __restrict__ pair,
                    const float* __restrict__ kern,
                    const float* __restrict__ bias,
                    float* __restrict__ out)
{
    __shared__ __bf16 Blds[32 * PITCH];   // B-half [i_local][k], 70 KB

    const int tid  = threadIdx.x;
    const int fh   = blockIdx.x & 1;          // feature half: cols fh*32..fh*32+31
    const int band = blockIdx.x >> 1;         // edge band

    // ---- stage this half of B = [kernel | bias] into LDS as bf16 ----
    // kern half: 16(b) x 32(i_local) x 16(j-quad) = 8192 quads
    for (int q = tid; q < 8192; q += 512) {
        const int j  = (q & 15) * 4;
        const int il = (q >> 4) & 31;
        const int b  = q >> 9;
        const float4 v = *reinterpret_cast<const float4*>(
            kern + b * 4096 + (fh * 32 + il) * 64 + j);
        bf16x4 w;
        w[0] = (__bf16)v.x; w[1] = (__bf16)v.y; w[2] = (__bf16)v.z; w[3] = (__bf16)v.w;
        *reinterpret_cast<bf16x4*>(Blds + il * PITCH + (b << 6) + j) = w;
    }
    // bias half: 32(i_local) x 16(j-quad) = 512 quads
    {
        const int q  = tid;
        const int j  = (q & 15) * 4;
        const int il = q >> 4;
        const float4 v = *reinterpret_cast<const float4*>(
            bias + (fh * 32 + il) * 64 + j);
        bf16x4 w;
        w[0] = (__bf16)v.x; w[1] = (__bf16)v.y; w[2] = (__bf16)v.z; w[3] = (__bf16)v.w;
        *reinterpret_cast<bf16x4*>(Blds + il * PITCH + 1024 + j) = w;
    }
    __syncthreads();   // the ONLY barrier in the kernel

    const int wave = tid >> 6;
    const int lane = tid & 63;
    const int l31  = lane & 31;
    const int half = lane >> 5;
    const int h8   = half * 8;

    const __bf16* __restrict__ Brow = Blds + l31 * PITCH;   // feature fh*32 + l31

    const int r0 = (NR * band) / NBANDS;
    const int r1 = (NR * (band + 1)) / NBANDS;

    for (int u = r0 + wave; u < r1; u += 8) {
        const int p0 = u * 32;
        int p1 = p0 + 32; if (p1 > NEDGES) p1 = NEDGES;
        const int s = first_break(pair, p0, lane);
        const int e = first_break(pair, p1, lane);
        if (s >= e) continue;   // a long segment swallowed this window

        int carryTgt = INT_MIN;
        f32x16 c;
        #pragma unroll
        for (int r = 0; r < 16; ++r) c[r] = 0.f;

        for (int g = s; g < e; g += 32) {
            // IR-level fence: forbid hoisting the loop-invariant B-fragment
            // ds_reads (and nb/bd loads) out of this loop — LICM of 68
            // invariant ds_read_b128 results (272 VGPRs) rematerializes
            // through scratch and was the R5/R6 450 MB HBM mystery traffic.
            asm volatile("" ::: "memory");

            const int w = (e - g < 32) ? (e - g) : 32;

            f32x16 acc; int myTgt; bool isLast;
            scan_slot(g, e, atom, bond, pair, Brow, l31, half, h8, acc, myTgt, isLast);

            if (myTgt == carryTgt) {
                #pragma unroll
                for (int r = 0; r < 16; ++r) acc[r] += c[r];
            }

            const int lastTgt = __shfl(myTgt, w - 1, 32);
            const bool cont = (g + 32 < e) && (lastTgt == pair[2 * (g + 32)]);

            const bool owner = isLast && !(cont && (l31 == w - 1));
            if (owner) {
                float* o = out + (long)myTgt * AD + fh * 32;
                #pragma unroll
                for (int rq = 0; rq < 4; ++rq) {
                    float4 v;
                    v.x = acc[rq*4+0]; v.y = acc[rq*4+1]; v.z = acc[rq*4+2]; v.w = acc[rq*4+3];
                    *reinterpret_cast<float4*>(o + 8 * rq + 4 * half) = v;
                }
            }

            if (cont) {   // wave-uniform branch
                #pragma unroll
                for (int r = 0; r < 16; ++r) c[r] = __shfl(acc[r], w - 1, 32);
                carryTgt = lastTgt;
            } else {
                carryTgt = INT_MIN;
            }
        }
    }
}

extern "C" void kernel_launch(void* const* d_in, const int* in_sizes, int n_in,
                              void* d_out, int out_size, void* d_ws, size_t ws_size,
                              hipStream_t stream) {
    const float* atom = (const float*)d_in[0];
    const float* bond = (const float*)d_in[1];
    const int*   pair = (const int*)d_in[2];
    const float* kern = (const float*)d_in[3];
    const float* bias = (const float*)d_in[4];
    float* out = (float*)d_out;

    hipMemsetAsync(d_out, 0, (size_t)out_size * sizeof(float), stream);

    edgenet_kernel<<<NBLK, 512, 0, stream>>>(atom, bond, pair, kern, bias, out);
}

// Round 8
// 65.873 us; speedup vs baseline: 4.4630x; 1.0624x over previous
//
#include <hip/hip_runtime.h>
#include <hip/hip_bf16.h>
#include <climits>

#define NATOMS 50000
#define NEDGES 100000
#define AD 64
#define BD 16
#define PITCH 1096            // LDS row pitch in bf16 elems (1088 + 8)
#define NR ((NEDGES + 31) / 32)   // 3125 wave-ranges of 32 edges
#define NBANDS 256
#define NBLK (NBANDS * 2)     // x2 feature-halves; 2 blocks/CU co-resident

typedef __bf16 bf16x8 __attribute__((ext_vector_type(8)));
typedef __bf16 bf16x4 __attribute__((ext_vector_type(4)));
typedef float  f32x16 __attribute__((ext_vector_type(16)));

// smallest "break" index >= p (break: q==0, q==NEDGES, or tgt[q]!=tgt[q-1]).
__device__ __forceinline__ int first_break(const int* __restrict__ pair, int p, const int lane) {
    while (true) {
        const int q = p + lane;
        bool brk;
        if (q == 0 || q >= NEDGES) brk = true;
        else brk = (pair[2 * q] != pair[2 * q - 2]);
        const unsigned long long m = __ballot(brk);
        if (m) {
            int r = p + (int)__builtin_ctzll(m);
            return r > NEDGES ? NEDGES : r;
        }
        p += 64;
    }
}

// MFMA + in-wave segmented inclusive scan over one chunk [g, g+32) ∩ [, e)
// for 32 features (this block's half). C[feature][edge], edge = l31.
__device__ __forceinline__ void scan_slot(
    const int g, const int e,
    const float* __restrict__ atom, const float* __restrict__ bond,
    const int* __restrict__ pair,
    const __bf16* __restrict__ Brow,
    const int l31, const int half, const int h8,
    f32x16& acc, int& myTgt, bool& isLast)
{
    const int eA = g + l31;
    const bool validE = (eA < e);
    const int eAc = validE ? eA : 0;

    int ni = pair[2 * eAc + 1];
    if ((unsigned)ni >= NATOMS) ni = 0;
    const float* nbrRow  = atom + (long)ni * AD;
    const float* bondRow = bond + (long)eAc * BD;

    // half-row of nbr this lane needs: j = 16q + 8*half + r
    // (invalid lanes' garbage is never consumed: tgt=INT_MAX never matches)
    float nb[4][8];
    #pragma unroll
    for (int q = 0; q < 4; ++q) {
        const float4 lo = *reinterpret_cast<const float4*>(nbrRow + q * 16 + h8);
        const float4 hi = *reinterpret_cast<const float4*>(nbrRow + q * 16 + h8 + 4);
        nb[q][0] = lo.x; nb[q][1] = lo.y; nb[q][2] = lo.z; nb[q][3] = lo.w;
        nb[q][4] = hi.x; nb[q][5] = hi.y; nb[q][6] = hi.z; nb[q][7] = hi.w;
    }
    float bd[16];
    #pragma unroll
    for (int q = 0; q < 4; ++q) {
        const float4 v = *reinterpret_cast<const float4*>(bondRow + q * 4);
        bd[q * 4 + 0] = v.x; bd[q * 4 + 1] = v.y;
        bd[q * 4 + 2] = v.z; bd[q * 4 + 3] = v.w;
    }

    #pragma unroll
    for (int r = 0; r < 16; ++r) acc[r] = 0.f;

    // main K: k = 16t + 8*half + r ;  b = t>>2 ; j = 16*(t&3) + 8*half + r
    #pragma unroll
    for (int t = 0; t < 64; ++t) {
        const float bv = bd[t >> 2];
        bf16x8 a;
        #pragma unroll
        for (int r = 0; r < 8; ++r) a[r] = (__bf16)(bv * nb[t & 3][r]);
        const bf16x8 b0 = *reinterpret_cast<const bf16x8*>(Brow + t * 16 + h8);
        acc = __builtin_amdgcn_mfma_f32_32x32x16_bf16(b0, a, acc, 0, 0, 0);
    }
    #pragma unroll
    for (int t = 64; t < 68; ++t) {   // bias rows, A-side vector = nbr
        bf16x8 a;
        #pragma unroll
        for (int r = 0; r < 8; ++r) a[r] = (__bf16)(nb[t - 64][r]);
        const bf16x8 b0 = *reinterpret_cast<const bf16x8*>(Brow + t * 16 + h8);
        acc = __builtin_amdgcn_mfma_f32_32x32x16_bf16(b0, a, acc, 0, 0, 0);
    }

    // segmented inclusive scan over sorted tgt within the 32-lane group
    myTgt = validE ? pair[2 * eA] : INT_MAX;
    #pragma unroll
    for (int d = 1; d < 32; d <<= 1) {
        const int srcTgt = __shfl_up(myTgt, (unsigned)d, 32);
        const bool same = (l31 >= d) && (srcTgt == myTgt);
        #pragma unroll
        for (int r = 0; r < 16; ++r) {
            const float v = __shfl_up(acc[r], (unsigned)d, 32);
            if (same) acc[r] += v;
        }
    }

    const int nTgt = __shfl_down(myTgt, 1u, 32);
    isLast = validE && ((l31 == 31) || (nTgt != myTgt));
}

__global__ __launch_bounds__(512, 2)
void edgenet_kernel(const float* __restrict__ atom,
                    const float* __restrict__ bond,
                    const int*   __restrict__ pair,
                    const float* __restrict__ kern,
                    const float* __restrict__ bias,
                    float* __restrict__ out)
{
    __shared__ __bf16 Blds[32 * PITCH];   // B-half [i_local][k], 70 KB

    const int tid  = threadIdx.x;
    const int fh   = blockIdx.x & 1;          // feature half: cols fh*32..fh*32+31
    const int band = blockIdx.x >> 1;         // edge band

    // ---- stage this half of B = [kernel | bias] into LDS as bf16 ----
    // kern half: 16(b) x 32(i_local) x 16(j-quad) = 8192 quads
    for (int q = tid; q < 8192; q += 512) {
        const int j  = (q & 15) * 4;
        const int il = (q >> 4) & 31;
        const int b  = q >> 9;
        const float4 v = *reinterpret_cast<const float4*>(
            kern + b * 4096 + (fh * 32 + il) * 64 + j);
        bf16x4 w;
        w[0] = (__bf16)v.x; w[1] = (__bf16)v.y; w[2] = (__bf16)v.z; w[3] = (__bf16)v.w;
        *reinterpret_cast<bf16x4*>(Blds + il * PITCH + (b << 6) + j) = w;
    }
    // bias half: 32(i_local) x 16(j-quad) = 512 quads
    {
        const int q  = tid;
        const int j  = (q & 15) * 4;
        const int il = q >> 4;
        const float4 v = *reinterpret_cast<const float4*>(
            bias + (fh * 32 + il) * 64 + j);
        bf16x4 w;
        w[0] = (__bf16)v.x; w[1] = (__bf16)v.y; w[2] = (__bf16)v.z; w[3] = (__bf16)v.w;
        *reinterpret_cast<bf16x4*>(Blds + il * PITCH + 1024 + j) = w;
    }
    __syncthreads();   // the ONLY barrier in the kernel

    const int wave = tid >> 6;
    const int lane = tid & 63;
    const int l31  = lane & 31;
    const int half = lane >> 5;
    const int h8   = half * 8;

    const __bf16* __restrict__ Brow = Blds + l31 * PITCH;   // feature fh*32 + l31

    const int r0 = (NR * band) / NBANDS;
    const int r1 = (NR * (band + 1)) / NBANDS;

    for (int u = r0 + wave; u < r1; u += 8) {
        const int p0 = u * 32;
        int p1 = p0 + 32; if (p1 > NEDGES) p1 = NEDGES;
        const int s = first_break(pair, p0, lane);
        const int e = first_break(pair, p1, lane);
        if (s >= e) continue;   // a long segment swallowed this window

        int carryTgt = INT_MIN;
        f32x16 c;
        #pragma unroll
        for (int r = 0; r < 16; ++r) c[r] = 0.f;

        for (int g = s; g < e; g += 32) {
            // IR-level fence: forbid hoisting the loop-invariant B-fragment
            // ds_reads (and nb/bd loads) out of this loop — LICM of 68
            // invariant ds_read_b128 results rematerializes through scratch
            // and was the R5/R6 450 MB HBM mystery traffic.
            asm volatile("" ::: "memory");

            const int w = (e - g < 32) ? (e - g) : 32;

            f32x16 acc; int myTgt; bool isLast;
            scan_slot(g, e, atom, bond, pair, Brow, l31, half, h8, acc, myTgt, isLast);

            if (myTgt == carryTgt) {
                #pragma unroll
                for (int r = 0; r < 16; ++r) acc[r] += c[r];
            }

            const int lastTgt = __shfl(myTgt, w - 1, 32);
            const bool cont = (g + 32 < e) && (lastTgt == pair[2 * (g + 32)]);

            const bool owner = isLast && !(cont && (l31 == w - 1));
            if (owner) {
                float* o = out + (long)myTgt * AD + fh * 32;
                #pragma unroll
                for (int rq = 0; rq < 4; ++rq) {
                    float4 v;
                    v.x = acc[rq*4+0]; v.y = acc[rq*4+1]; v.z = acc[rq*4+2]; v.w = acc[rq*4+3];
                    *reinterpret_cast<float4*>(o + 8 * rq + 4 * half) = v;
                }
            }

            if (cont) {   // wave-uniform branch
                #pragma unroll
                for (int r = 0; r < 16; ++r) c[r] = __shfl(acc[r], w - 1, 32);
                carryTgt = lastTgt;
            } else {
                carryTgt = INT_MIN;
            }
        }
    }
}

extern "C" void kernel_launch(void* const* d_in, const int* in_sizes, int n_in,
                              void* d_out, int out_size, void* d_ws, size_t ws_size,
                              hipStream_t stream) {
    const float* atom = (const float*)d_in[0];
    const float* bond = (const float*)d_in[1];
    const int*   pair = (const int*)d_in[2];
    const float* kern = (const float*)d_in[3];
    const float* bias = (const float*)d_in[4];
    float* out = (float*)d_out;

    hipMemsetAsync(d_out, 0, (size_t)out_size * sizeof(float), stream);

    edgenet_kernel<<<NBLK, 512, 0, stream>>>(atom, bond, pair, kern, bias, out);
}

// Round 9
// 54.259 us; speedup vs baseline: 5.4182x; 1.2140x over previous
//
#include <hip/hip_runtime.h>
#include <hip/hip_bf16.h>
#include <climits>

#define NATOMS 50000
#define NEDGES 100000
#define AD 64
#define BD 16
#define PITCH 1096            // LDS row pitch in bf16 elems (1088 + 8)
#define NR ((NEDGES + 31) / 32)   // 3125 wave-ranges of 32 edges
#define NBANDS 256

typedef __bf16 bf16x8 __attribute__((ext_vector_type(8)));
typedef __bf16 bf16x4 __attribute__((ext_vector_type(4)));
typedef float  f32x16 __attribute__((ext_vector_type(16)));

// smallest "break" index >= p (break: q==0, q==NEDGES, or tgt[q]!=tgt[q-1]).
__device__ __forceinline__ int first_break(const int* __restrict__ pair, int p, const int lane) {
    while (true) {
        const int q = p + lane;
        bool brk;
        if (q == 0 || q >= NEDGES) brk = true;
        else brk = (pair[2 * q] != pair[2 * q - 2]);
        const unsigned long long m = __ballot(brk);
        if (m) {
            int r = p + (int)__builtin_ctzll(m);
            return r > NEDGES ? NEDGES : r;
        }
        p += 64;
    }
}

// MFMA + in-wave segmented inclusive scan over one chunk [g, g+32) ∩ [, e)
// for ALL 64 features. C[feature][edge], edge = l31; acc0 = features 0..31,
// acc1 = features 32..63, f = (r&3)+8*(r>>2)+4*half (+32 for acc1).
__device__ __forceinline__ void scan_slot(
    const int g, const int e,
    const float* __restrict__ atom, const float* __restrict__ bond,
    const int* __restrict__ pair,
    const __bf16* __restrict__ Brow0, const __bf16* __restrict__ Brow1,
    const int l31, const int half, const int h8,
    f32x16& acc0, f32x16& acc1, int& myTgt, bool& isLast)
{
    const int eA = g + l31;
    const bool validE = (eA < e);
    const int eAc = validE ? eA : 0;

    int ni = pair[2 * eAc + 1];
    if ((unsigned)ni >= NATOMS) ni = 0;
    const float* nbrRow  = atom + (long)ni * AD;
    const float* bondRow = bond + (long)eAc * BD;

    // half-row of nbr this lane needs: j = 16q + 8*half + r
    // (invalid lanes' garbage is never consumed: tgt=INT_MAX never matches)
    float nb[4][8];
    #pragma unroll
    for (int q = 0; q < 4; ++q) {
        const float4 lo = *reinterpret_cast<const float4*>(nbrRow + q * 16 + h8);
        const float4 hi = *reinterpret_cast<const float4*>(nbrRow + q * 16 + h8 + 4);
        nb[q][0] = lo.x; nb[q][1] = lo.y; nb[q][2] = lo.z; nb[q][3] = lo.w;
        nb[q][4] = hi.x; nb[q][5] = hi.y; nb[q][6] = hi.z; nb[q][7] = hi.w;
    }
    float bd[16];
    #pragma unroll
    for (int q = 0; q < 4; ++q) {
        const float4 v = *reinterpret_cast<const float4*>(bondRow + q * 4);
        bd[q * 4 + 0] = v.x; bd[q * 4 + 1] = v.y;
        bd[q * 4 + 2] = v.z; bd[q * 4 + 3] = v.w;
    }

    #pragma unroll
    for (int r = 0; r < 16; ++r) { acc0[r] = 0.f; acc1[r] = 0.f; }

    // main K: k = 16t + 8*half + r ;  b = t>>2 ; j = 16*(t&3) + 8*half + r
    // ONE a-fragment feeds BOTH feature-half MFMAs (the whole point).
    #pragma unroll
    for (int t = 0; t < 64; ++t) {
        const float bv = bd[t >> 2];
        bf16x8 a;
        #pragma unroll
        for (int r = 0; r < 8; ++r) a[r] = (__bf16)(bv * nb[t & 3][r]);
        const int k0 = t * 16 + h8;
        const bf16x8 b0 = *reinterpret_cast<const bf16x8*>(Brow0 + k0);
        const bf16x8 b1 = *reinterpret_cast<const bf16x8*>(Brow1 + k0);
        acc0 = __builtin_amdgcn_mfma_f32_32x32x16_bf16(b0, a, acc0, 0, 0, 0);
        acc1 = __builtin_amdgcn_mfma_f32_32x32x16_bf16(b1, a, acc1, 0, 0, 0);
    }
    #pragma unroll
    for (int t = 64; t < 68; ++t) {   // bias rows, A-side vector = nbr
        bf16x8 a;
        #pragma unroll
        for (int r = 0; r < 8; ++r) a[r] = (__bf16)(nb[t - 64][r]);
        const int k0 = t * 16 + h8;
        const bf16x8 b0 = *reinterpret_cast<const bf16x8*>(Brow0 + k0);
        const bf16x8 b1 = *reinterpret_cast<const bf16x8*>(Brow1 + k0);
        acc0 = __builtin_amdgcn_mfma_f32_32x32x16_bf16(b0, a, acc0, 0, 0, 0);
        acc1 = __builtin_amdgcn_mfma_f32_32x32x16_bf16(b1, a, acc1, 0, 0, 0);
    }

    // segmented inclusive scan over sorted tgt within the 32-lane group.
    // Steps 1,2,4 always; steps 8,16 only if some segment length >= 9
    // (correct: steps 1+2+4 give back-reach 7, enough for seglen <= 8).
    myTgt = validE ? pair[2 * eA] : INT_MAX;
    #pragma unroll
    for (int d = 1; d <= 4; d <<= 1) {
        const int srcTgt = __shfl_up(myTgt, (unsigned)d, 32);
        const bool same = (l31 >= d) && (srcTgt == myTgt);
        #pragma unroll
        for (int r = 0; r < 16; ++r) {
            const float v0 = __shfl_up(acc0[r], (unsigned)d, 32);
            const float v1 = __shfl_up(acc1[r], (unsigned)d, 32);
            if (same) { acc0[r] += v0; acc1[r] += v1; }
        }
    }
    const int src8 = __shfl_up(myTgt, 8u, 32);
    if (__any((l31 >= 8) && (src8 == myTgt))) {
        const bool same8 = (l31 >= 8) && (src8 == myTgt);
        #pragma unroll
        for (int r = 0; r < 16; ++r) {
            const float v0 = __shfl_up(acc0[r], 8u, 32);
            const float v1 = __shfl_up(acc1[r], 8u, 32);
            if (same8) { acc0[r] += v0; acc1[r] += v1; }
        }
        const int src16 = __shfl_up(myTgt, 16u, 32);
        const bool same16 = (l31 >= 16) && (src16 == myTgt);
        #pragma unroll
        for (int r = 0; r < 16; ++r) {
            const float v0 = __shfl_up(acc0[r], 16u, 32);
            const float v1 = __shfl_up(acc1[r], 16u, 32);
            if (same16) { acc0[r] += v0; acc1[r] += v1; }
        }
    }

    const int nTgt = __shfl_down(myTgt, 1u, 32);
    isLast = validE && ((l31 == 31) || (nTgt != myTgt));
}

__global__ __launch_bounds__(1024, 1)
void edgenet_kernel(const float* __restrict__ atom,
                    const float* __restrict__ bond,
                    const int*   __restrict__ pair,
                    const float* __restrict__ kern,
                    const float* __restrict__ bias,
                    float* __restrict__ out)
{
    __shared__ __bf16 Blds[64 * PITCH];   // full B [i][k], 140 KB
    __shared__ float  Crow[16][64];       // per-wave carry row (LDS, not VGPRs)

    const int tid  = threadIdx.x;
    const int band = blockIdx.x;

    // ---- stage B = [kernel | bias] into LDS as bf16 ----
    for (int q = tid; q < (16 * 4096) / 4; q += 1024) {
        const int idx = q * 4;                  // flat: b*4096 + i*64 + j
        const int b = idx >> 12;
        const int i = (idx >> 6) & 63;
        const int j = idx & 63;
        const float4 v = *reinterpret_cast<const float4*>(kern + idx);
        bf16x4 w;
        w[0] = (__bf16)v.x; w[1] = (__bf16)v.y; w[2] = (__bf16)v.z; w[3] = (__bf16)v.w;
        *reinterpret_cast<bf16x4*>(Blds + i * PITCH + (b << 6) + j) = w;
    }
    {   // bias: exactly 1024 quads
        const int q = tid;
        const int idx = q * 4;
        const int i = idx >> 6;
        const int j = idx & 63;
        const float4 v = *reinterpret_cast<const float4*>(bias + idx);
        bf16x4 w;
        w[0] = (__bf16)v.x; w[1] = (__bf16)v.y; w[2] = (__bf16)v.z; w[3] = (__bf16)v.w;
        *reinterpret_cast<bf16x4*>(Blds + i * PITCH + 1024 + j) = w;
    }
    __syncthreads();   // the ONLY barrier in the kernel

    const int wave = tid >> 6;
    const int lane = tid & 63;
    const int l31  = lane & 31;
    const int half = lane >> 5;
    const int h8   = half * 8;

    const __bf16* __restrict__ Brow0 = Blds + l31 * PITCH;         // features 0..31
    const __bf16* __restrict__ Brow1 = Blds + (32 + l31) * PITCH;  // features 32..63

    const int r0 = (NR * band) / NBANDS;
    const int r1 = (NR * (band + 1)) / NBANDS;

    for (int u = r0 + wave; u < r1; u += 16) {
        const int p0 = u * 32;
        int p1 = p0 + 32; if (p1 > NEDGES) p1 = NEDGES;
        const int s = first_break(pair, p0, lane);
        const int e = first_break(pair, p1, lane);
        if (s >= e) continue;   // a long segment swallowed this window

        int carryTgt = INT_MIN;   // wave-uniform

        for (int g = s; g < e; g += 32) {
            // IR-level fence: forbid LICM of the loop-invariant B-fragment
            // ds_reads (rematerialization through scratch was the R5/R6
            // mystery HBM traffic).
            asm volatile("" ::: "memory");

            const int w = (e - g < 32) ? (e - g) : 32;

            f32x16 acc0, acc1; int myTgt; bool isLast;
            scan_slot(g, e, atom, bond, pair, Brow0, Brow1,
                      l31, half, h8, acc0, acc1, myTgt, isLast);

            // fold in carry (post-scan: only owner's value is consumed)
            if (carryTgt != INT_MIN) {      // wave-uniform guard
                const bool m = (myTgt == carryTgt);
                #pragma unroll
                for (int r = 0; r < 16; ++r) {
                    const int f = (r & 3) + 8 * (r >> 2) + 4 * half;
                    const float c0 = Crow[wave][f];        // LDS broadcast
                    const float c1 = Crow[wave][32 + f];
                    if (m) { acc0[r] += c0; acc1[r] += c1; }
                }
            }

            const int lastTgt = __shfl(myTgt, w - 1, 32);
            const bool cont = (g + 32 < e) && (lastTgt == pair[2 * (g + 32)]);

            const bool owner = isLast && !(cont && (l31 == w - 1));
            if (owner) {
                float* o = out + (long)myTgt * AD;
                #pragma unroll
                for (int rq = 0; rq < 4; ++rq) {
                    float4 v0, v1;
                    v0.x = acc0[rq*4+0]; v0.y = acc0[rq*4+1]; v0.z = acc0[rq*4+2]; v0.w = acc0[rq*4+3];
                    v1.x = acc1[rq*4+0]; v1.y = acc1[rq*4+1]; v1.z = acc1[rq*4+2]; v1.w = acc1[rq*4+3];
                    *reinterpret_cast<float4*>(o + 8 * rq + 4 * half)      = v0;
                    *reinterpret_cast<float4*>(o + 32 + 8 * rq + 4 * half) = v1;
                }
            }

            if (cont) {   // wave-uniform branch: stash tail row in LDS
                if (l31 == w - 1) {   // 2 lanes (one per half)
                    #pragma unroll
                    for (int r = 0; r < 16; ++r) {
                        const int f = (r & 3) + 8 * (r >> 2) + 4 * half;
                        Crow[wave][f]      = acc0[r];
                        Crow[wave][32 + f] = acc1[r];
                    }
                }
                carryTgt = lastTgt;
            } else {
                carryTgt = INT_MIN;
            }
        }
    }
}

extern "C" void kernel_launch(void* const* d_in, const int* in_sizes, int n_in,
                              void* d_out, int out_size, void* d_ws, size_t ws_size,
                              hipStream_t stream) {
    const float* atom = (const float*)d_in[0];
    const float* bond = (const float*)d_in[1];
    const int*   pair = (const int*)d_in[2];
    const float* kern = (const float*)d_in[3];
    const float* bias = (const float*)d_in[4];
    float* out = (float*)d_out;

    hipMemsetAsync(d_out, 0, (size_t)out_size * sizeof(float), stream);

    edgenet_kernel<<<NBANDS, 1024, 0, stream>>>(atom, bond, pair, kern, bias, out);
}